// Round 1
// baseline (637.264 us; speedup 1.0000x reference)
//
#include <hip/hip_runtime.h>
#include <hip/hip_bf16.h>
#include <stdint.h>

#define B_DIM 8192
#define IN_DIM 4096
#define OUT_DIM 4096

typedef __attribute__((ext_vector_type(8))) short s16x8;
typedef __attribute__((ext_vector_type(4))) float f32x4;

__device__ __forceinline__ unsigned short f2bf_rn(float f) {
    unsigned int u = __float_as_uint(f);
    u = (u + 0x7FFFu + ((u >> 16) & 1u)) >> 16;
    return (unsigned short)u;
}

__device__ __forceinline__ void async16(unsigned short* l, const unsigned short* g) {
    __builtin_amdgcn_global_load_lds(
        (const __attribute__((address_space(1))) void*)g,
        (__attribute__((address_space(3))) void*)l, 16, 0, 0);
}

// ---- Kernel 1: per-output-channel weight quantization -----------------------
// One block per output channel o. Computes fc_sf[o] (written straight to d_out
// region 2), w_int as bf16 (exact: integers in [-128,127]), and
// bb[o] = round(b/bias_sf)*bias_sf. Block 0 thread 0 zeroes the global max.
__global__ __launch_bounds__(256) void quant_w(
    const float* __restrict__ W, const float* __restrict__ b,
    const float* __restrict__ act_sf, unsigned short* __restrict__ wq,
    float* __restrict__ fc_sf_out, float* __restrict__ bb,
    float* __restrict__ gmax)
{
    int o = blockIdx.x;
    int t = threadIdx.x;
    const float4* Wr = (const float4*)(W + (size_t)o * IN_DIM);
    float4 v[4];
    float amax = 0.f;
#pragma unroll
    for (int j = 0; j < 4; ++j) {
        v[j] = Wr[t + j * 256];
        amax = fmaxf(amax, fmaxf(fmaxf(fabsf(v[j].x), fabsf(v[j].y)),
                                 fmaxf(fabsf(v[j].z), fabsf(v[j].w))));
    }
#pragma unroll
    for (int off = 32; off > 0; off >>= 1)
        amax = fmaxf(amax, __shfl_down(amax, off, 64));
    __shared__ float red[4];
    if ((t & 63) == 0) red[t >> 6] = amax;
    __syncthreads();
    float wmax = fmaxf(fmaxf(red[0], red[1]), fmaxf(red[2], red[3]));
    float sf = fmaxf(wmax, 1e-8f) / 127.0f;   // fc_sf, matches ref fp32 ops

    unsigned short* wr = wq + (size_t)o * IN_DIM;
#pragma unroll
    for (int j = 0; j < 4; ++j) {
        ushort4 q;
        q.x = f2bf_rn(fminf(fmaxf(rintf(v[j].x / sf), -128.f), 127.f));
        q.y = f2bf_rn(fminf(fmaxf(rintf(v[j].y / sf), -128.f), 127.f));
        q.z = f2bf_rn(fminf(fmaxf(rintf(v[j].z / sf), -128.f), 127.f));
        q.w = f2bf_rn(fminf(fmaxf(rintf(v[j].w / sf), -128.f), 127.f));
        ((ushort4*)wr)[t + j * 256] = q;
    }
    if (t == 0) {
        fc_sf_out[o] = sf;
        float bsf = sf * act_sf[0];          // bias_sf
        float bi = rintf(b[o] / bsf);        // b_int
        bb[o] = bi * bsf;                    // folded bias for epilogue
        if (o == 0) gmax[0] = 0.f;           // ws is poisoned 0xAA each launch
    }
}

// ---- Kernel 2: x -> bf16 (RN) ----------------------------------------------
__global__ __launch_bounds__(256) void cvt_x(const float* __restrict__ x,
                                             unsigned short* __restrict__ xq)
{
    size_t i = ((size_t)blockIdx.x * 256 + threadIdx.x) * 4;
    float4 v = *(const float4*)(x + i);
    ushort4 q;
    q.x = f2bf_rn(v.x); q.y = f2bf_rn(v.y);
    q.z = f2bf_rn(v.z); q.w = f2bf_rn(v.w);
    *(ushort4*)(xq + i) = q;
}

// ---- Kernel 3: GEMM C = A * B^T, fused scale+bias+ReLU+global-max ----------
// A = x bf16 [M][K], Bw = w_int bf16 [N][K]. m97 structure: 128x128 tile,
// BK=32, 4 waves each computing 64x64 via 4x4 16x16x32 MFMA.
__global__ __launch_bounds__(256) void gemm_bt(
    const unsigned short* __restrict__ A, const unsigned short* __restrict__ Bw,
    const float* __restrict__ fc_sf, const float* __restrict__ bb,
    float* __restrict__ C, float* __restrict__ gmax)
{
    __shared__ unsigned short sA[128 * 32];
    __shared__ unsigned short sB[128 * 32];
    __shared__ float redm[4];

    int t = threadIdx.x;
    int bn = blockIdx.x & 31;      // N/128 = 32
    int bm = blockIdx.x >> 5;      // M/128 = 64
    int lane = t & 63;
    int w = t >> 6;
    int quad = lane >> 4;
    int l16 = lane & 15;
    int m0 = bm * 128, n0 = bn * 128;
    int wm = (w & 1) * 64, wn = (w >> 1) * 64;

    // staging: chunk c = t (i=0), t+256 (i=1); row = c>>2, kchunk = c&3
    // LDS dest = base + lane*16 (wave-uniform base) -> unpadded row-major tile
    const unsigned short* gA0 = A + (size_t)(m0 + (t >> 2)) * IN_DIM + (t & 3) * 8;
    const unsigned short* gA1 = A + (size_t)(m0 + 64 + (t >> 2)) * IN_DIM + (t & 3) * 8;
    const unsigned short* gB0 = Bw + (size_t)(n0 + (t >> 2)) * IN_DIM + (t & 3) * 8;
    const unsigned short* gB1 = Bw + (size_t)(n0 + 64 + (t >> 2)) * IN_DIM + (t & 3) * 8;
    unsigned short* lA0 = sA + t * 8;
    unsigned short* lA1 = sA + (t + 256) * 8;
    unsigned short* lB0 = sB + t * 8;
    unsigned short* lB1 = sB + (t + 256) * 8;

    // fragment read bases: A[m=l16][k=quad*8+j], B[n=l16][k=quad*8+j]
    const unsigned short* pa = sA + (wm + l16) * 32 + quad * 8;
    const unsigned short* pb = sB + (wn + l16) * 32 + quad * 8;

    f32x4 acc[4][4];
#pragma unroll
    for (int mi = 0; mi < 4; ++mi)
#pragma unroll
        for (int ni = 0; ni < 4; ++ni)
            acc[mi][ni] = (f32x4){0.f, 0.f, 0.f, 0.f};

    for (int kk = 0; kk < IN_DIM; kk += 32) {
        __syncthreads();                       // all waves done reading prev tile
        async16(lA0, gA0 + kk);
        async16(lA1, gA1 + kk);
        async16(lB0, gB0 + kk);
        async16(lB1, gB1 + kk);
        asm volatile("s_waitcnt vmcnt(0)" ::: "memory");
        __syncthreads();

        s16x8 af[4], bf[4];
#pragma unroll
        for (int i = 0; i < 4; ++i) af[i] = *(const s16x8*)(pa + i * 16 * 32);
#pragma unroll
        for (int i = 0; i < 4; ++i) bf[i] = *(const s16x8*)(pb + i * 16 * 32);
#pragma unroll
        for (int mi = 0; mi < 4; ++mi)
#pragma unroll
            for (int ni = 0; ni < 4; ++ni)
                acc[mi][ni] = __builtin_amdgcn_mfma_f32_16x16x32_bf16(
                    af[mi], bf[ni], acc[mi][ni], 0, 0, 0);
    }

    // epilogue: C/D layout col = lane&15, row = quad*4 + reg
    float tmax = 0.f;
#pragma unroll
    for (int ni = 0; ni < 4; ++ni) {
        int col = n0 + wn + ni * 16 + l16;
        float s = fc_sf[col];
        float bbv = bb[col];
#pragma unroll
        for (int mi = 0; mi < 4; ++mi) {
            int rowb = m0 + wm + mi * 16 + quad * 4;
#pragma unroll
            for (int r = 0; r < 4; ++r) {
                float vv = acc[mi][ni][r] * s + bbv;
                vv = fmaxf(vv, 0.f);           // ReLU
                tmax = fmaxf(tmax, vv);
                C[(size_t)(rowb + r) * OUT_DIM + col] = vv;
            }
        }
    }
#pragma unroll
    for (int off = 32; off > 0; off >>= 1)
        tmax = fmaxf(tmax, __shfl_down(tmax, off, 64));
    if (lane == 0) redm[w] = tmax;
    __syncthreads();
    if (t == 0) {
        float bmax = fmaxf(fmaxf(redm[0], redm[1]), fmaxf(redm[2], redm[3]));
        // all values >= 0: fp32 ordering == int ordering
        atomicMax((int*)gmax, __float_as_int(bmax));
    }
}

// ---- Kernel 4: per-tensor requant, in place on d_out -----------------------
// x_min = 0 exactly (post-ReLU), so zp = 0.
__global__ __launch_bounds__(256) void requant(float* __restrict__ C,
    const float* __restrict__ gmax, float* __restrict__ sf_out)
{
    float sf = fmaxf(gmax[0], 1e-8f) / 255.0f;
    size_t i = ((size_t)blockIdx.x * 256 + threadIdx.x) * 4;
    float4 v = *(const float4*)(C + i);
    v.x = fminf(rintf(v.x / sf), 255.f) * sf;
    v.y = fminf(rintf(v.y / sf), 255.f) * sf;
    v.z = fminf(rintf(v.z / sf), 255.f) * sf;
    v.w = fminf(rintf(v.w / sf), 255.f) * sf;
    *(float4*)(C + i) = v;
    if (i == 0) sf_out[0] = sf;
}

extern "C" void kernel_launch(void* const* d_in, const int* in_sizes, int n_in,
                              void* d_out, int out_size, void* d_ws, size_t ws_size,
                              hipStream_t stream)
{
    const float* x      = (const float*)d_in[0];
    const float* act_sf = (const float*)d_in[1];
    const float* W      = (const float*)d_in[2];
    const float* b      = (const float*)d_in[3];

    float* out        = (float*)d_out;                       // [8192*4096] x_out
    float* fc_sf_out  = out + (size_t)B_DIM * OUT_DIM;       // [4096]
    float* act_sf_out = fc_sf_out + OUT_DIM;                 // [1]

    char* ws = (char*)d_ws;
    float* bb   = (float*)ws;                                // 4096 floats
    float* gmax = (float*)(ws + 16384);                      // 1 float
    unsigned short* xq = (unsigned short*)(ws + 32768);      // x bf16 [8192][4096]
    unsigned short* wq = xq + (size_t)B_DIM * IN_DIM;        // w_int bf16 [4096][4096]

    quant_w<<<OUT_DIM, 256, 0, stream>>>(W, b, act_sf, wq, fc_sf_out, bb, gmax);
    cvt_x<<<(B_DIM * IN_DIM) / 1024, 256, 0, stream>>>(x, xq);
    gemm_bt<<<(B_DIM / 128) * (OUT_DIM / 128), 256, 0, stream>>>(
        xq, wq, fc_sf_out, bb, out, gmax);
    requant<<<(B_DIM * OUT_DIM) / 1024, 256, 0, stream>>>(out, gmax, act_sf_out);
}